// Round 5
// baseline (203.573 us; speedup 1.0000x reference)
//
#include <hip/hip_runtime.h>

#define D 64
#define K3 192  // 3*D
#define OUTD 64
#define CHUNK 1024  // elements per scan block (256 thr x 4)
#define BM 128      // nodes per out_gemm block

// ---------------------------------------------------------------------------
// Pass 1: histogram of dst -> counts[N]
// ---------------------------------------------------------------------------
__global__ void hist_kernel(const int* __restrict__ dst,
                            int* __restrict__ counts, int E) {
    int i = blockIdx.x * blockDim.x + threadIdx.x;
    if (i < E) atomicAdd(&counts[dst[i]], 1);
}

// ---------------------------------------------------------------------------
// Pass 2a: per-chunk reduce -> chunksum[nchunks]
// ---------------------------------------------------------------------------
__global__ __launch_bounds__(256) void scan_chunk_reduce(
        const int* __restrict__ counts, int* __restrict__ chunksum, int N) {
    int base = blockIdx.x * CHUNK;
    int t = threadIdx.x;
    int idx = base + t * 4;
    int s = 0;
    if (idx + 3 < N) {
        int4 v = *(const int4*)&counts[idx];
        s = v.x + v.y + v.z + v.w;
    } else {
        for (int j = 0; j < 4; ++j)
            if (idx + j < N) s += counts[idx + j];
    }
#pragma unroll
    for (int o = 32; o >= 1; o >>= 1) s += __shfl_xor(s, o);
    __shared__ int wt[4];
    if ((t & 63) == 0) wt[t >> 6] = s;
    __syncthreads();
    if (t == 0) chunksum[blockIdx.x] = wt[0] + wt[1] + wt[2] + wt[3];
}

// ---------------------------------------------------------------------------
// Pass 2b: single-block exclusive scan of chunksums (nchunks <= 256).
// ---------------------------------------------------------------------------
__global__ __launch_bounds__(256) void scan_chunksums(
        int* __restrict__ chunksum, int nchunks, int* __restrict__ offsN) {
    __shared__ int sh[256];
    int t = threadIdx.x;
    int v = (t < nchunks) ? chunksum[t] : 0;
    sh[t] = v;
    __syncthreads();
    for (int o = 1; o < 256; o <<= 1) {
        int u = (t >= o) ? sh[t - o] : 0;
        __syncthreads();
        sh[t] += u;
        __syncthreads();
    }
    if (t < nchunks) chunksum[t] = sh[t] - v;   // exclusive
    if (t == nchunks - 1) *offsN = sh[t];       // total = E
}

// ---------------------------------------------------------------------------
// Pass 2c: per-chunk apply -> offs, cursor.
// ---------------------------------------------------------------------------
__global__ __launch_bounds__(256) void scan_chunk_apply(
        int* __restrict__ counts,             // in: counts, out: offs
        const int* __restrict__ chunkbase,    // exclusive chunk prefixes
        int* __restrict__ cursor, int N) {
    int base = blockIdx.x * CHUNK;
    int t = threadIdx.x;
    int lane = t & 63;
    int wid = t >> 6;
    int idx = base + t * 4;
    int v[4] = {0, 0, 0, 0};
    if (idx + 3 < N) {
        int4 x = *(const int4*)&counts[idx];
        v[0] = x.x; v[1] = x.y; v[2] = x.z; v[3] = x.w;
    } else {
        for (int j = 0; j < 4; ++j)
            if (idx + j < N) v[j] = counts[idx + j];
    }
    int s = v[0] + v[1] + v[2] + v[3];
    int incl = s;
#pragma unroll
    for (int o = 1; o < 64; o <<= 1) {
        int u = __shfl_up(incl, o);
        if (lane >= o) incl += u;
    }
    __shared__ int wt[4];
    if (lane == 63) wt[wid] = incl;
    __syncthreads();
    int wbase = 0;
    for (int j = 0; j < wid; ++j) wbase += wt[j];
    int run = chunkbase[blockIdx.x] + wbase + (incl - s);
    for (int j = 0; j < 4; ++j) {
        int ij = idx + j;
        if (ij < N) {
            counts[ij] = run;
            cursor[ij] = run;
            run += v[j];
        }
    }
}

// ---------------------------------------------------------------------------
// Pass 3: scatter edges into dst-sorted order; payload packed (w, src).
// ---------------------------------------------------------------------------
__global__ void scatter_kernel(const float* __restrict__ w,
                               const int* __restrict__ src,
                               const int* __restrict__ dst,
                               int* __restrict__ cursor,
                               uint2* __restrict__ e_pack, int E) {
    int i = blockIdx.x * blockDim.x + threadIdx.x;
    if (i >= E) return;
    int d = dst[i];
    int p = atomicAdd(&cursor[d], 1);
    e_pack[p] = make_uint2(__float_as_uint(w[i]), (unsigned)src[i]);
}

// ---------------------------------------------------------------------------
// Pass 4: fused per-node softmax (pos & neg) + aggregation. One wave/node.
// ---------------------------------------------------------------------------
__global__ __launch_bounds__(256) void node_agg_kernel(
        const float* __restrict__ feat,
        const int* __restrict__ offs,     // len N+1
        const uint2* __restrict__ e_pack,
        float* __restrict__ h_pos,
        float* __restrict__ h_neg, int N) {
    int lane = threadIdx.x & 63;
    int node = (blockIdx.x * blockDim.x + threadIdx.x) >> 6;
    if (node >= N) return;
    int beg = offs[node];
    int end = offs[node + 1];

    // Phase A: masked maxes
    float mp = -1e30f, mn = -1e30f;
    for (int base = beg; base < end; base += 64) {
        int e = base + lane;
        float we = (e < end) ? __uint_as_float(e_pack[e].x) : 0.0f;
        if (we > 0.0f) mp = fmaxf(mp, we);
        else if (we < 0.0f) mn = fmaxf(mn, -we);
    }
#pragma unroll
    for (int o = 32; o >= 1; o >>= 1) {
        mp = fmaxf(mp, __shfl_xor(mp, o));
        mn = fmaxf(mn, __shfl_xor(mn, o));
    }

    // Phase B: denominators
    float sp = 0.0f, sn = 0.0f;
    for (int base = beg; base < end; base += 64) {
        int e = base + lane;
        float we = (e < end) ? __uint_as_float(e_pack[e].x) : 0.0f;
        if (we > 0.0f) sp += __expf(we - mp);
        else if (we < 0.0f) sn += __expf(-we - mn);
    }
#pragma unroll
    for (int o = 32; o >= 1; o >>= 1) {
        sp += __shfl_xor(sp, o);
        sn += __shfl_xor(sn, o);
    }
    float rp = 1.0f / (sp + 1e-16f);
    float rn = 1.0f / (sn + 1e-16f);

    // Phase C: aggregation, wave-uniform scalar metadata loop
    float accp = 0.0f, accn = 0.0f;
    int ubeg = __builtin_amdgcn_readfirstlane(beg);
    int uend = __builtin_amdgcn_readfirstlane(end);
#pragma unroll 4
    for (int e = ubeg; e < uend; ++e) {
        uint2 pk = e_pack[e];               // wave-uniform -> s_load
        float wj = __uint_as_float(pk.x);
        int   sj = (int)pk.y;
        bool pos = wj > 0.0f;
        float m = pos ? mp : mn;
        float r = pos ? rp : rn;
        float aj = __expf(fabsf(wj) - m) * r;
        aj = (wj == 0.0f) ? 0.0f : aj;      // kill w==0 (and its inf path)
        float t = feat[(size_t)sj * D + lane] * aj;
        accp += pos ? t : 0.0f;
        accn += pos ? 0.0f : t;
    }
    h_pos[(size_t)node * D + lane] = accp;
    h_neg[(size_t)node * D + lane] = accn;
}

// ---------------------------------------------------------------------------
// Pass 5a: one-time transpose W_fc[o][k] -> Wt_g[k][o] (so out_gemm blocks
// can stage LDS with a coalesced, conflict-free linear copy).
// ---------------------------------------------------------------------------
__global__ void wt_transpose_kernel(const float* __restrict__ W_fc,
                                    float* __restrict__ Wt_g) {
    int i = blockIdx.x * blockDim.x + threadIdx.x;
    if (i < K3 * OUTD) {
        int o = i / K3;
        int k = i % K3;
        Wt_g[k * OUTD + o] = W_fc[i];
    }
}

// ---------------------------------------------------------------------------
// Pass 5b: output projection, register-blocked.
// Block = 128 threads, BM=128 nodes. Thread tile: 4 nodes x 16 outputs
// (og = tid&3 selects the 16-out group; quad = tid>>2 selects the 4 nodes).
// Each Wt float4 from LDS feeds 16 FMAs (4x reuse across nodes).
// ---------------------------------------------------------------------------
__global__ __launch_bounds__(128) void out_gemm_kernel(
        const float* __restrict__ feat,
        const float* __restrict__ h_pos,
        const float* __restrict__ h_neg,
        const float* __restrict__ Wt_g,   // [K3][OUTD]
        const float* __restrict__ b_fc,
        const float* __restrict__ bias,
        const float* __restrict__ coef_self,
        const float* __restrict__ coef_posi,
        const float* __restrict__ coef_nega,
        float* __restrict__ out,
        int N) {
    __shared__ float Wt[K3 * OUTD];  // 48 KiB
    {
        const float4* s4 = (const float4*)Wt_g;
        float4* d4 = (float4*)Wt;
        for (int i = threadIdx.x; i < K3 * OUTD / 4; i += 128) d4[i] = s4[i];
    }
    __syncthreads();

    int tid = threadIdx.x;
    int og = tid & 3;           // outputs [og*16, og*16+16)
    int quad = tid >> 2;        // nodes n0..n0+3
    int n0 = blockIdx.x * BM + quad * 4;

    float cf[3];
    cf[0] = coef_self[0];
    cf[1] = coef_posi[0];
    cf[2] = coef_nega[0];
    const float* segs[3];
    segs[0] = feat;
    segs[1] = h_pos;
    segs[2] = h_neg;

    // bias init (same 16 outputs for all 4 nodes)
    float binit[16];
#pragma unroll
    for (int j = 0; j < 16; j += 4) {
        float4 b1 = *(const float4*)&b_fc[og * 16 + j];
        float4 b2 = *(const float4*)&bias[og * 16 + j];
        binit[j + 0] = b1.x + b2.x;
        binit[j + 1] = b1.y + b2.y;
        binit[j + 2] = b1.z + b2.z;
        binit[j + 3] = b1.w + b2.w;
    }
    float acc[4][16];
#pragma unroll
    for (int nd = 0; nd < 4; ++nd)
#pragma unroll
        for (int j = 0; j < 16; ++j) acc[nd][j] = binit[j];

    for (int sg = 0; sg < 3; ++sg) {
        const float* base = segs[sg];
        float c = cf[sg];
#pragma unroll 4
        for (int kb = 0; kb < D / 4; ++kb) {  // 16 iterations of 4 k
            float4 cv[4];
#pragma unroll
            for (int nd = 0; nd < 4; ++nd) {
                int n = n0 + nd;
                if (n < N) {
                    float4 v = *(const float4*)&base[(size_t)n * D + kb * 4];
                    cv[nd] = make_float4(v.x * c, v.y * c, v.z * c, v.w * c);
                } else {
                    cv[nd] = make_float4(0.f, 0.f, 0.f, 0.f);
                }
            }
#pragma unroll
            for (int j = 0; j < 4; ++j) {
                const float* wrow = &Wt[(sg * D + kb * 4 + j) * OUTD + og * 16];
                float4 w0 = *(const float4*)&wrow[0];
                float4 w1 = *(const float4*)&wrow[4];
                float4 w2 = *(const float4*)&wrow[8];
                float4 w3 = *(const float4*)&wrow[12];
#pragma unroll
                for (int nd = 0; nd < 4; ++nd) {
                    float cj = (&cv[nd].x)[j];
                    acc[nd][0]  += cj * w0.x;
                    acc[nd][1]  += cj * w0.y;
                    acc[nd][2]  += cj * w0.z;
                    acc[nd][3]  += cj * w0.w;
                    acc[nd][4]  += cj * w1.x;
                    acc[nd][5]  += cj * w1.y;
                    acc[nd][6]  += cj * w1.z;
                    acc[nd][7]  += cj * w1.w;
                    acc[nd][8]  += cj * w2.x;
                    acc[nd][9]  += cj * w2.y;
                    acc[nd][10] += cj * w2.z;
                    acc[nd][11] += cj * w2.w;
                    acc[nd][12] += cj * w3.x;
                    acc[nd][13] += cj * w3.y;
                    acc[nd][14] += cj * w3.z;
                    acc[nd][15] += cj * w3.w;
                }
            }
        }
    }

#pragma unroll
    for (int nd = 0; nd < 4; ++nd) {
        int n = n0 + nd;
        if (n < N) {
            float* op = out + (size_t)n * OUTD + og * 16;
#pragma unroll
            for (int j = 0; j < 16; j += 4) {
                float4 r;
                r.x = acc[nd][j + 0];
                r.y = acc[nd][j + 1];
                r.z = acc[nd][j + 2];
                r.w = acc[nd][j + 3];
                *(float4*)&op[j] = r;
            }
        }
    }
}

extern "C" void kernel_launch(void* const* d_in, const int* in_sizes, int n_in,
                              void* d_out, int out_size, void* d_ws, size_t ws_size,
                              hipStream_t stream) {
    const float* feat      = (const float*)d_in[0];
    const float* w         = (const float*)d_in[1];
    const float* W_fc      = (const float*)d_in[2];
    const float* b_fc      = (const float*)d_in[3];
    const float* bias      = (const float*)d_in[4];
    const float* coef_self = (const float*)d_in[5];
    const float* coef_posi = (const float*)d_in[6];
    const float* coef_nega = (const float*)d_in[7];
    const int*   src       = (const int*)d_in[8];
    const int*   dst       = (const int*)d_in[9];

    const int E = in_sizes[1];
    const int N = in_sizes[0] / D;
    const int nchunks = (N + CHUNK - 1) / CHUNK;  // 49 for N=50000 (<=256 req.)

    // Workspace layout (4B elems, e_pack 8B-aligned):
    //   counts/offs [N+1] | cursor [N] | chunksum [256] | Wt_g [K3*OUTD]
    //   | pad | e_pack [E]x8B | h_pos [N*D] | h_neg [N*D]
    char* ws = (char*)d_ws;
    int*   counts   = (int*)ws;                                // becomes offs
    int*   cursor   = (int*)(ws + (size_t)(N + 1) * 4);
    int*   chunksum = (int*)(ws + (size_t)(2 * N + 1) * 4);
    float* Wt_g     = (float*)(ws + (size_t)(2 * N + 1 + 256) * 4);
    size_t epack_off = (((size_t)(2 * N + 1 + 256 + K3 * OUTD) * 4) + 7) & ~(size_t)7;
    uint2* e_pack   = (uint2*)(ws + epack_off);
    float* h_pos    = (float*)(ws + epack_off + (size_t)E * 8);
    float* h_neg    = h_pos + (size_t)N * D;

    // Zero only the histogram (everything else fully written each call).
    hipMemsetAsync(counts, 0, (size_t)N * 4, stream);

    int eb = (E + 255) / 256;
    wt_transpose_kernel<<<(K3 * OUTD + 255) / 256, 256, 0, stream>>>(W_fc, Wt_g);
    hist_kernel<<<eb, 256, 0, stream>>>(dst, counts, E);
    scan_chunk_reduce<<<nchunks, 256, 0, stream>>>(counts, chunksum, N);
    scan_chunksums<<<1, 256, 0, stream>>>(chunksum, nchunks, &counts[N]);
    scan_chunk_apply<<<nchunks, 256, 0, stream>>>(counts, chunksum, cursor, N);
    scatter_kernel<<<eb, 256, 0, stream>>>(w, src, dst, cursor, e_pack, E);

    int nb = (N * 64 + 255) / 256;
    node_agg_kernel<<<nb, 256, 0, stream>>>(feat, counts, e_pack, h_pos, h_neg, N);

    int gb = (N + BM - 1) / BM;
    out_gemm_kernel<<<gb, 128, 0, stream>>>(feat, h_pos, h_neg, Wt_g, b_fc, bias,
                                            coef_self, coef_posi, coef_nega,
                                            (float*)d_out, N);
}

// Round 6
// 160.595 us; speedup vs baseline: 1.2676x; 1.2676x over previous
//
#include <hip/hip_runtime.h>

#define D 64
#define K3 192  // 3*D
#define OUTD 64
#define CHUNK 1024  // elements per scan block (256 thr x 4)

typedef __attribute__((ext_vector_type(8))) short bf16x8;
typedef __attribute__((ext_vector_type(4))) float f32x4;

static __device__ __forceinline__ unsigned short f2bf(float f) {
    unsigned u = __float_as_uint(f);
    u += 0x7fffu + ((u >> 16) & 1u);  // round-to-nearest-even
    return (unsigned short)(u >> 16);
}

// ---------------------------------------------------------------------------
// Pass 1: histogram of dst -> counts[N]
// ---------------------------------------------------------------------------
__global__ void hist_kernel(const int* __restrict__ dst,
                            int* __restrict__ counts, int E) {
    int i = blockIdx.x * blockDim.x + threadIdx.x;
    if (i < E) atomicAdd(&counts[dst[i]], 1);
}

// ---------------------------------------------------------------------------
// Pass 2a: per-chunk reduce -> chunksum[nchunks]
// ---------------------------------------------------------------------------
__global__ __launch_bounds__(256) void scan_chunk_reduce(
        const int* __restrict__ counts, int* __restrict__ chunksum, int N) {
    int base = blockIdx.x * CHUNK;
    int t = threadIdx.x;
    int idx = base + t * 4;
    int s = 0;
    if (idx + 3 < N) {
        int4 v = *(const int4*)&counts[idx];
        s = v.x + v.y + v.z + v.w;
    } else {
        for (int j = 0; j < 4; ++j)
            if (idx + j < N) s += counts[idx + j];
    }
#pragma unroll
    for (int o = 32; o >= 1; o >>= 1) s += __shfl_xor(s, o);
    __shared__ int wt[4];
    if ((t & 63) == 0) wt[t >> 6] = s;
    __syncthreads();
    if (t == 0) chunksum[blockIdx.x] = wt[0] + wt[1] + wt[2] + wt[3];
}

// ---------------------------------------------------------------------------
// Pass 2b: single-block exclusive scan of chunksums (nchunks <= 256).
// ---------------------------------------------------------------------------
__global__ __launch_bounds__(256) void scan_chunksums(
        int* __restrict__ chunksum, int nchunks, int* __restrict__ offsN) {
    __shared__ int sh[256];
    int t = threadIdx.x;
    int v = (t < nchunks) ? chunksum[t] : 0;
    sh[t] = v;
    __syncthreads();
    for (int o = 1; o < 256; o <<= 1) {
        int u = (t >= o) ? sh[t - o] : 0;
        __syncthreads();
        sh[t] += u;
        __syncthreads();
    }
    if (t < nchunks) chunksum[t] = sh[t] - v;   // exclusive
    if (t == nchunks - 1) *offsN = sh[t];       // total = E
}

// ---------------------------------------------------------------------------
// Pass 2c: per-chunk apply -> offs, cursor.
// ---------------------------------------------------------------------------
__global__ __launch_bounds__(256) void scan_chunk_apply(
        int* __restrict__ counts,             // in: counts, out: offs
        const int* __restrict__ chunkbase,    // exclusive chunk prefixes
        int* __restrict__ cursor, int N) {
    int base = blockIdx.x * CHUNK;
    int t = threadIdx.x;
    int lane = t & 63;
    int wid = t >> 6;
    int idx = base + t * 4;
    int v[4] = {0, 0, 0, 0};
    if (idx + 3 < N) {
        int4 x = *(const int4*)&counts[idx];
        v[0] = x.x; v[1] = x.y; v[2] = x.z; v[3] = x.w;
    } else {
        for (int j = 0; j < 4; ++j)
            if (idx + j < N) v[j] = counts[idx + j];
    }
    int s = v[0] + v[1] + v[2] + v[3];
    int incl = s;
#pragma unroll
    for (int o = 1; o < 64; o <<= 1) {
        int u = __shfl_up(incl, o);
        if (lane >= o) incl += u;
    }
    __shared__ int wt[4];
    if (lane == 63) wt[wid] = incl;
    __syncthreads();
    int wbase = 0;
    for (int j = 0; j < wid; ++j) wbase += wt[j];
    int run = chunkbase[blockIdx.x] + wbase + (incl - s);
    for (int j = 0; j < 4; ++j) {
        int ij = idx + j;
        if (ij < N) {
            counts[ij] = run;
            cursor[ij] = run;
            run += v[j];
        }
    }
}

// ---------------------------------------------------------------------------
// Pass 3: scatter edges into dst-sorted order; payload packed (w, src).
// ---------------------------------------------------------------------------
__global__ void scatter_kernel(const float* __restrict__ w,
                               const int* __restrict__ src,
                               const int* __restrict__ dst,
                               int* __restrict__ cursor,
                               uint2* __restrict__ e_pack, int E) {
    int i = blockIdx.x * blockDim.x + threadIdx.x;
    if (i >= E) return;
    int d = dst[i];
    int p = atomicAdd(&cursor[d], 1);
    e_pack[p] = make_uint2(__float_as_uint(w[i]), (unsigned)src[i]);
}

// ---------------------------------------------------------------------------
// Pass 4: fused per-node softmax (pos & neg) + aggregation. One wave/node.
// ---------------------------------------------------------------------------
__global__ __launch_bounds__(256) void node_agg_kernel(
        const float* __restrict__ feat,
        const int* __restrict__ offs,     // len N+1
        const uint2* __restrict__ e_pack,
        float* __restrict__ h_pos,
        float* __restrict__ h_neg, int N) {
    int lane = threadIdx.x & 63;
    int node = (blockIdx.x * blockDim.x + threadIdx.x) >> 6;
    if (node >= N) return;
    int beg = offs[node];
    int end = offs[node + 1];

    // Phase A: masked maxes
    float mp = -1e30f, mn = -1e30f;
    for (int base = beg; base < end; base += 64) {
        int e = base + lane;
        float we = (e < end) ? __uint_as_float(e_pack[e].x) : 0.0f;
        if (we > 0.0f) mp = fmaxf(mp, we);
        else if (we < 0.0f) mn = fmaxf(mn, -we);
    }
#pragma unroll
    for (int o = 32; o >= 1; o >>= 1) {
        mp = fmaxf(mp, __shfl_xor(mp, o));
        mn = fmaxf(mn, __shfl_xor(mn, o));
    }

    // Phase B: denominators
    float sp = 0.0f, sn = 0.0f;
    for (int base = beg; base < end; base += 64) {
        int e = base + lane;
        float we = (e < end) ? __uint_as_float(e_pack[e].x) : 0.0f;
        if (we > 0.0f) sp += __expf(we - mp);
        else if (we < 0.0f) sn += __expf(-we - mn);
    }
#pragma unroll
    for (int o = 32; o >= 1; o >>= 1) {
        sp += __shfl_xor(sp, o);
        sn += __shfl_xor(sn, o);
    }
    float rp = 1.0f / (sp + 1e-16f);
    float rn = 1.0f / (sn + 1e-16f);

    // Phase C: aggregation, wave-uniform scalar metadata loop
    float accp = 0.0f, accn = 0.0f;
    int ubeg = __builtin_amdgcn_readfirstlane(beg);
    int uend = __builtin_amdgcn_readfirstlane(end);
#pragma unroll 4
    for (int e = ubeg; e < uend; ++e) {
        uint2 pk = e_pack[e];               // wave-uniform -> s_load
        float wj = __uint_as_float(pk.x);
        int   sj = (int)pk.y;
        bool pos = wj > 0.0f;
        float m = pos ? mp : mn;
        float r = pos ? rp : rn;
        float aj = __expf(fabsf(wj) - m) * r;
        aj = (wj == 0.0f) ? 0.0f : aj;      // kill w==0 (and its inf path)
        float t = feat[(size_t)sj * D + lane] * aj;
        accp += pos ? t : 0.0f;
        accn += pos ? 0.0f : t;
    }
    h_pos[(size_t)node * D + lane] = accp;
    h_neg[(size_t)node * D + lane] = accn;
}

// ---------------------------------------------------------------------------
// Pass 5a (one-time): bake W_fc[o][k] into MFMA B-fragment layout, bf16.
// Bfrag idx = ((kt*4 + nt)*64 + lane)*8 + j  holds  W_fc^T[k][n] where
//   n = nt*16 + (lane&15),  k = kt*32 + (lane>>4)*8 + j.
// ---------------------------------------------------------------------------
__global__ void build_bfrag_kernel(const float* __restrict__ W_fc,
                                   unsigned short* __restrict__ Bfrag) {
    int i = blockIdx.x * blockDim.x + threadIdx.x;
    if (i >= 6 * 4 * 64 * 8) return;
    int j    = i & 7;
    int lane = (i >> 3) & 63;
    int nt   = (i >> 9) & 3;
    int kt   = i >> 11;
    int n = nt * 16 + (lane & 15);
    int k = kt * 32 + (lane >> 4) * 8 + j;
    Bfrag[i] = f2bf(W_fc[n * K3 + k]);
}

// ---------------------------------------------------------------------------
// Pass 5b: output projection via MFMA. One wave per 16 nodes.
// A tile 16x32 gathered f32->bf16 from {feat,h_pos,h_neg} (scaled by coef);
// B fragments preloaded (24 x dwordx4, L1-resident); 6 k-steps x 4 n-tiles
// of v_mfma_f32_16x16x32_bf16. D layout: col=lane&15, row=4*(lane>>4)+reg.
// ---------------------------------------------------------------------------
__global__ __launch_bounds__(256) void out_gemm_mfma(
        const float* __restrict__ feat,
        const float* __restrict__ h_pos,
        const float* __restrict__ h_neg,
        const unsigned short* __restrict__ Bfrag,
        const float* __restrict__ b_fc,
        const float* __restrict__ bias,
        const float* __restrict__ coef_self,
        const float* __restrict__ coef_posi,
        const float* __restrict__ coef_nega,
        float* __restrict__ out,
        int N) {
    int lane = threadIdx.x & 63;
    int wv = (blockIdx.x * blockDim.x + threadIdx.x) >> 6;
    int node0 = wv * 16;
    if (node0 >= N) return;

    // preload all 24 B fragments (16B/lane each, coalesced)
    const bf16x8* bp = (const bf16x8*)Bfrag;
    bf16x8 bfr[24];
#pragma unroll
    for (int f = 0; f < 24; ++f) bfr[f] = bp[f * 64 + lane];

    float cf[3];
    cf[0] = coef_self[0];
    cf[1] = coef_posi[0];
    cf[2] = coef_nega[0];
    const float* segs[3];
    segs[0] = feat;
    segs[1] = h_pos;
    segs[2] = h_neg;

    int m = lane & 15;          // A row / D col
    int kg = lane >> 4;         // k-group
    int node = node0 + m;
    bool mvalid = node < N;

    f32x4 acc[4];
#pragma unroll
    for (int nt = 0; nt < 4; ++nt) acc[nt] = (f32x4){0.f, 0.f, 0.f, 0.f};

#pragma unroll
    for (int kt = 0; kt < 6; ++kt) {
        int sg = kt >> 1;
        float c = cf[sg];
        const float* srcp = segs[sg] + (size_t)node * D + (kt & 1) * 32 + kg * 8;
        float v[8];
        if (mvalid) {
            float4 v0 = *(const float4*)(srcp);
            float4 v1 = *(const float4*)(srcp + 4);
            v[0] = v0.x; v[1] = v0.y; v[2] = v0.z; v[3] = v0.w;
            v[4] = v1.x; v[5] = v1.y; v[6] = v1.z; v[7] = v1.w;
        } else {
#pragma unroll
            for (int j = 0; j < 8; ++j) v[j] = 0.f;
        }
        bf16x8 a;
#pragma unroll
        for (int j = 0; j < 8; ++j) a[j] = (short)f2bf(v[j] * c);
#pragma unroll
        for (int nt = 0; nt < 4; ++nt)
            acc[nt] = __builtin_amdgcn_mfma_f32_16x16x32_bf16(
                a, bfr[kt * 4 + nt], acc[nt], 0, 0, 0);
    }

    // epilogue: bias + store. D element (row=4*kg+j, col=m) in acc[nt][j].
#pragma unroll
    for (int nt = 0; nt < 4; ++nt) {
        int col = nt * 16 + m;
        float bb = b_fc[col] + bias[col];
#pragma unroll
        for (int j = 0; j < 4; ++j) {
            int row = node0 + 4 * kg + j;
            if (row < N) out[(size_t)row * OUTD + col] = acc[nt][j] + bb;
        }
    }
}

extern "C" void kernel_launch(void* const* d_in, const int* in_sizes, int n_in,
                              void* d_out, int out_size, void* d_ws, size_t ws_size,
                              hipStream_t stream) {
    const float* feat      = (const float*)d_in[0];
    const float* w         = (const float*)d_in[1];
    const float* W_fc      = (const float*)d_in[2];
    const float* b_fc      = (const float*)d_in[3];
    const float* bias      = (const float*)d_in[4];
    const float* coef_self = (const float*)d_in[5];
    const float* coef_posi = (const float*)d_in[6];
    const float* coef_nega = (const float*)d_in[7];
    const int*   src       = (const int*)d_in[8];
    const int*   dst       = (const int*)d_in[9];

    const int E = in_sizes[1];
    const int N = in_sizes[0] / D;
    const int nchunks = (N + CHUNK - 1) / CHUNK;  // 49 for N=50000 (<=256 req.)

    // Workspace layout (4B elems; e_pack 8B-aligned, Bfrag 16B-aligned):
    //   counts/offs [N+1] | cursor [N] | chunksum [256] | Bfrag [12288 u16]
    //   | pad | e_pack [E]x8B | h_pos [N*D] | h_neg [N*D]
    char* ws = (char*)d_ws;
    int*   counts   = (int*)ws;                                // becomes offs
    int*   cursor   = (int*)(ws + (size_t)(N + 1) * 4);
    int*   chunksum = (int*)(ws + (size_t)(2 * N + 1) * 4);
    size_t bfrag_off = (((size_t)(2 * N + 1 + 256) * 4) + 15) & ~(size_t)15;
    unsigned short* Bfrag = (unsigned short*)(ws + bfrag_off);
    size_t epack_off = (bfrag_off + 6 * 4 * 64 * 8 * 2 + 7) & ~(size_t)7;
    uint2* e_pack   = (uint2*)(ws + epack_off);
    float* h_pos    = (float*)(ws + epack_off + (size_t)E * 8);
    float* h_neg    = h_pos + (size_t)N * D;

    // Zero only the histogram (everything else fully written each call).
    hipMemsetAsync(counts, 0, (size_t)N * 4, stream);

    int eb = (E + 255) / 256;
    build_bfrag_kernel<<<(6 * 4 * 64 * 8 + 255) / 256, 256, 0, stream>>>(W_fc, Bfrag);
    hist_kernel<<<eb, 256, 0, stream>>>(dst, counts, E);
    scan_chunk_reduce<<<nchunks, 256, 0, stream>>>(counts, chunksum, N);
    scan_chunksums<<<1, 256, 0, stream>>>(chunksum, nchunks, &counts[N]);
    scan_chunk_apply<<<nchunks, 256, 0, stream>>>(counts, chunksum, cursor, N);
    scatter_kernel<<<eb, 256, 0, stream>>>(w, src, dst, cursor, e_pack, E);

    int nb = (N * 64 + 255) / 256;
    node_agg_kernel<<<nb, 256, 0, stream>>>(feat, counts, e_pack, h_pos, h_neg, N);

    int nwaves = (N + 15) / 16;
    int gb = (nwaves + 3) / 4;  // 4 waves per 256-thread block
    out_gemm_mfma<<<gb, 256, 0, stream>>>(feat, h_pos, h_neg, Bfrag, b_fc, bias,
                                          coef_self, coef_posi, coef_nega,
                                          (float*)d_out, N);
}